// Round 1
// baseline (87.583 us; speedup 1.0000x reference)
//
#include <hip/hip_runtime.h>
#include <hip/hip_bf16.h>

#define NN 4096
#define DD 768
#define CCL 97
#define KBN 24               // DD/32 k-blocks

typedef __attribute__((ext_vector_type(8))) short bf16x8;
typedef __attribute__((ext_vector_type(4))) float f32x4;

// workspace layout (bytes)
#define SZ_FT    (NN*DD*2)                // 6291456, bf16 fragment-tiled F
#define OFF_R    (SZ_FT)
#define OFF_S    (OFF_R + NN*4)
#define OFF_C    (OFF_S + NN*4)
#define OFF_M    (OFF_C + NN*4)
#define OFF_BITS (OFF_M + NN*4)           // 4096 * 16B
#define OFF_LM   (OFF_BITS + NN*16)

__device__ __forceinline__ unsigned fkey(float x) {
  unsigned u = __float_as_uint(x);
  return (u & 0x80000000u) ? ~u : (u | 0x80000000u);
}

// one wave per row: pack 97 labels into 2x u64 via ballot; label_mask
__global__ void prep_bits_kernel(const int* __restrict__ labels,
                                 ulonglong2* __restrict__ bits,
                                 float* __restrict__ lm) {
  int gw = (blockIdx.x * blockDim.x + threadIdx.x) >> 6;
  int lane = threadIdx.x & 63;
  if (gw >= NN) return;
  const int* lr = labels + (long)gw * CCL;
  int v0 = lr[lane];                       // lane < 64 < 97 always valid
  int c1 = 64 + lane;
  int v1 = (c1 < CCL) ? lr[c1] : 0;
  unsigned long long m0 = __ballot(v0 == 1);
  unsigned long long m1 = __ballot(v1 == 1);
  if (lane == 0) {
    bits[gw] = make_ulonglong2(m0, m1);
    lm[gw] = (lr[0] != 1) ? 1.0f : 0.0f;
  }
}

// f32 [N][D] -> bf16 fragment-tiled:
// tile t = g*KBN + kb (g = row/16, kb = k/32); within tile chunk c = ko*16 + ro
// bf16 index = t*512 + c*8 + e  where row = g*16+ro, k = kb*32 + ko*8 + e
__global__ void convert_kernel(const float* __restrict__ F, short* __restrict__ Ft) {
  int idx = blockIdx.x * 256 + threadIdx.x;      // one 8-elem chunk per thread
  int t = idx >> 6, c = idx & 63;
  int ko = c >> 4, ro = c & 15;
  int g = t / KBN, kb = t - g * KBN;
  int row = g * 16 + ro;
  int k0 = kb * 32 + ko * 8;
  const float* src = F + (long)row * DD + k0;
  union { __hip_bfloat16 h[8]; uint4 u; } p;
#pragma unroll
  for (int j = 0; j < 8; ++j) p.h[j] = __float2bfloat16(src[j]);
  *((uint4*)(Ft + (long)idx * 8)) = p.u;
}

__global__ __launch_bounds__(256) void main_kernel(
    const short* __restrict__ Ft, const ulonglong2* __restrict__ bits,
    float* __restrict__ R, float* __restrict__ S, float* __restrict__ Cc,
    unsigned int* __restrict__ Mk) {
  const int brow = blockIdx.y, bcol = blockIdx.x;
  const int tid = threadIdx.x;
  const int wave = tid >> 6, lane = tid & 63;
  const int wm = wave >> 1, wn = wave & 1;
  const int gi0 = brow * 8 + wm * 4;   // row groups -> B operand
  const int gj0 = bcol * 8 + wn * 4;   // col groups -> A operand

  f32x4 acc[4][4];                      // [fj][fi]
#pragma unroll
  for (int a = 0; a < 4; ++a)
#pragma unroll
    for (int b = 0; b < 4; ++b) acc[a][b] = (f32x4){0.f, 0.f, 0.f, 0.f};

  const short* pa = Ft + gj0 * (KBN * 512) + lane * 8;
  const short* pb = Ft + gi0 * (KBN * 512) + lane * 8;

  bf16x8 a0[4], b0[4], a1[4], b1[4];
#pragma unroll
  for (int f = 0; f < 4; ++f) {
    a0[f] = *(const bf16x8*)(pa + f * (KBN * 512));
    b0[f] = *(const bf16x8*)(pb + f * (KBN * 512));
  }
#pragma unroll
  for (int it = 0; it < 12; ++it) {
    const int kb1 = 2 * it + 1;
#pragma unroll
    for (int f = 0; f < 4; ++f) {
      a1[f] = *(const bf16x8*)(pa + f * (KBN * 512) + kb1 * 512);
      b1[f] = *(const bf16x8*)(pb + f * (KBN * 512) + kb1 * 512);
    }
#pragma unroll
    for (int fj = 0; fj < 4; ++fj)
#pragma unroll
      for (int fi = 0; fi < 4; ++fi)
        acc[fj][fi] = __builtin_amdgcn_mfma_f32_16x16x32_bf16(a0[fj], b0[fi], acc[fj][fi], 0, 0, 0);
    if (it < 11) {
      const int kbn = 2 * it + 2;
#pragma unroll
      for (int f = 0; f < 4; ++f) {
        a0[f] = *(const bf16x8*)(pa + f * (KBN * 512) + kbn * 512);
        b0[f] = *(const bf16x8*)(pb + f * (KBN * 512) + kbn * 512);
      }
    }
#pragma unroll
    for (int fj = 0; fj < 4; ++fj)
#pragma unroll
      for (int fi = 0; fi < 4; ++fi)
        acc[fj][fi] = __builtin_amdgcn_mfma_f32_16x16x32_bf16(a1[fj], b1[fi], acc[fj][fi], 0, 0, 0);
  }

  // epilogue: D[m][n] = sims[row = rowbase + fi*16 + (lane&15)][col = colbase + fj*16 + (lane>>4)*4 + reg]
  const int rowbase = brow * 128 + wm * 64;
  const int colbase = bcol * 128 + wn * 64;
  const int ln = lane & 15, lh = lane >> 4;

  float rs[4] = {0.f, 0.f, 0.f, 0.f};
  float ss[4] = {0.f, 0.f, 0.f, 0.f};
  float cs[4] = {0.f, 0.f, 0.f, 0.f};
  float mx[4] = {-1e30f, -1e30f, -1e30f, -1e30f};
  ulonglong2 rb[4];
  int rowv[4];
#pragma unroll
  for (int fi = 0; fi < 4; ++fi) {
    rowv[fi] = rowbase + fi * 16 + ln;
    rb[fi] = bits[rowv[fi]];
  }
#pragma unroll
  for (int fj = 0; fj < 4; ++fj) {
#pragma unroll
    for (int reg = 0; reg < 4; ++reg) {
      const int col = colbase + fj * 16 + lh * 4 + reg;
      const ulonglong2 cb = bits[col];
#pragma unroll
      for (int fi = 0; fi < 4; ++fi) {
        float v = acc[fj][fi][reg] * 0.5f;   // sims = dot / TAU
        float e = __expf(v);
        bool diag = (col == rowv[fi]);
        bool ovl = ((rb[fi].x & cb.x) | (rb[fi].y & cb.y)) != 0ULL;
        mx[fi] = fmaxf(mx[fi], v);
        if (!diag) {
          rs[fi] += e;
          if (ovl) { ss[fi] += v; cs[fi] += 1.0f; }
        }
      }
    }
  }
#pragma unroll
  for (int fi = 0; fi < 4; ++fi) {
    float r = rs[fi], s = ss[fi], c = cs[fi], m = mx[fi];
    r += __shfl_xor(r, 16, 64); s += __shfl_xor(s, 16, 64);
    c += __shfl_xor(c, 16, 64); m = fmaxf(m, __shfl_xor(m, 16, 64));
    r += __shfl_xor(r, 32, 64); s += __shfl_xor(s, 32, 64);
    c += __shfl_xor(c, 32, 64); m = fmaxf(m, __shfl_xor(m, 32, 64));
    if (lane < 16) {
      int row = rowbase + fi * 16 + lane;
      atomicAdd(R + row, r);
      atomicAdd(S + row, s);
      atomicAdd(Cc + row, c);
      atomicMax(Mk + row, fkey(m));
    }
  }
}

__global__ void finalize_kernel(const float* __restrict__ R, const float* __restrict__ S,
                                const float* __restrict__ Cc, const unsigned* __restrict__ Mk,
                                const float* __restrict__ lm, float* __restrict__ out) {
  int tid = threadIdx.x;
  float s1 = 0.f, s2 = 0.f, slm = 0.f;
  for (int i = tid; i < NN; i += 256) {
    float r = R[i], s = S[i], c = Cc[i], l = lm[i];
    float logR = logf(r);
    float lp1 = (c > 0.f) ? (s - c * logR) / c : 0.f;
    unsigned k = Mk[i];
    float m = (k & 0x80000000u) ? __uint_as_float(k & 0x7fffffffu) : __uint_as_float(~k);
    float lp2 = (c == 0.f) ? (m - logR) : 0.f;   // -log(row_sum) = M - log(R0)
    s1 += lp1 * l; s2 += lp2; slm += l;
  }
#pragma unroll
  for (int d = 1; d < 64; d <<= 1) {
    s1 += __shfl_xor(s1, d, 64);
    s2 += __shfl_xor(s2, d, 64);
    slm += __shfl_xor(slm, d, 64);
  }
  __shared__ float w1[4], w2[4], w3[4];
  int w = tid >> 6;
  if ((tid & 63) == 0) { w1[w] = s1; w2[w] = s2; w3[w] = slm; }
  __syncthreads();
  if (tid == 0) {
    float a = 0.f, b = 0.f, c2 = 0.f;
    for (int i = 0; i < 4; ++i) { a += w1[i]; b += w2[i]; c2 += w3[i]; }
    const float inv = 1.0f / (float)NN;
    out[0] = -2.0f * (a * inv + b * c2 * inv * inv);
  }
}

extern "C" void kernel_launch(void* const* d_in, const int* in_sizes, int n_in,
                              void* d_out, int out_size, void* d_ws, size_t ws_size,
                              hipStream_t stream) {
  const float* F = (const float*)d_in[0];
  const int* labels = (const int*)d_in[1];
  float* out = (float*)d_out;
  char* ws = (char*)d_ws;

  short* Ft = (short*)(ws);
  float* R = (float*)(ws + OFF_R);
  float* S = (float*)(ws + OFF_S);
  float* Cc = (float*)(ws + OFF_C);
  unsigned* Mk = (unsigned*)(ws + OFF_M);
  ulonglong2* bits = (ulonglong2*)(ws + OFF_BITS);
  float* lm = (float*)(ws + OFF_LM);

  // zero R, S, C, M (contiguous 4 * NN * 4 bytes); key 0 < key(-inf) so max-init ok
  hipMemsetAsync(ws + OFF_R, 0, 4 * NN * 4, stream);
  prep_bits_kernel<<<NN / 4, 256, 0, stream>>>(labels, bits, lm);
  convert_kernel<<<(NN * DD / 8) / 256, 256, 0, stream>>>(F, Ft);
  dim3 grid(32, 32);
  main_kernel<<<grid, 256, 0, stream>>>(Ft, bits, R, S, Cc, Mk);
  finalize_kernel<<<1, 256, 0, stream>>>(R, S, Cc, Mk, lm, out);
}

// Round 2
// 87.245 us; speedup vs baseline: 1.0039x; 1.0039x over previous
//
#include <hip/hip_runtime.h>
#include <hip/hip_bf16.h>

#define NN 4096
#define DD 768
#define CCL 97
#define KBN 24               // DD/32 k-blocks

typedef __attribute__((ext_vector_type(8))) short bf16x8;
typedef __attribute__((ext_vector_type(4))) float f32x4;

// workspace layout (bytes)
#define SZ_FT    (NN*DD*2)                // 6291456, bf16 fragment-tiled F
#define OFF_R    (SZ_FT)
#define OFF_S    (OFF_R + NN*4)
#define OFF_C    (OFF_S + NN*4)
#define OFF_M    (OFF_C + NN*4)
#define OFF_BITS (OFF_M + NN*4)           // 4096 * 16B
#define OFF_LM   (OFF_BITS + NN*16)

__device__ __forceinline__ unsigned fkey(float x) {
  unsigned u = __float_as_uint(x);
  return (u & 0x80000000u) ? ~u : (u | 0x80000000u);
}

// one wave per row: pack 97 labels into 2x u64 via ballot; label_mask
__global__ void prep_bits_kernel(const int* __restrict__ labels,
                                 ulonglong2* __restrict__ bits,
                                 float* __restrict__ lm) {
  int gw = (blockIdx.x * blockDim.x + threadIdx.x) >> 6;
  int lane = threadIdx.x & 63;
  if (gw >= NN) return;
  const int* lr = labels + (long)gw * CCL;
  int v0 = lr[lane];                       // lane < 64 < 97 always valid
  int c1 = 64 + lane;
  int v1 = (c1 < CCL) ? lr[c1] : 0;
  unsigned long long m0 = __ballot(v0 == 1);
  unsigned long long m1 = __ballot(v1 == 1);
  if (lane == 0) {
    bits[gw] = make_ulonglong2(m0, m1);
    lm[gw] = (lr[0] != 1) ? 1.0f : 0.0f;
  }
}

// f32 [N][D] -> bf16 fragment-tiled:
// tile t = g*KBN + kb (g = row/16, kb = k/32); within tile chunk c = ko*16 + ro
// bf16 index = t*512 + c*8 + e  where row = g*16+ro, k = kb*32 + ko*8 + e
__global__ void convert_kernel(const float* __restrict__ F, short* __restrict__ Ft) {
  int idx = blockIdx.x * 256 + threadIdx.x;      // one 8-elem chunk per thread
  int t = idx >> 6, c = idx & 63;
  int ko = c >> 4, ro = c & 15;
  int g = t / KBN, kb = t - g * KBN;
  int row = g * 16 + ro;
  int k0 = kb * 32 + ko * 8;
  const float* src = F + (long)row * DD + k0;
  union { __hip_bfloat16 h[8]; uint4 u; } p;
#pragma unroll
  for (int j = 0; j < 8; ++j) p.h[j] = __float2bfloat16(src[j]);
  *((uint4*)(Ft + (long)idx * 8)) = p.u;
}

__device__ __forceinline__ void gload_lds16(const short* gsrc, short* ldst) {
  __builtin_amdgcn_global_load_lds(
      (const __attribute__((address_space(1))) void*)gsrc,
      (__attribute__((address_space(3))) void*)ldst, 16, 0, 0);
}

// upper-triangle 128x128 blocks; LDS-staged panels; row stats + (off-diag) col stats
__global__ __launch_bounds__(256) void main_kernel(
    const short* __restrict__ Ft, const ulonglong2* __restrict__ bits,
    float* __restrict__ R, float* __restrict__ S, float* __restrict__ Cc,
    unsigned int* __restrict__ Mk) {
  const int bcol = blockIdx.x, brow = blockIdx.y;
  if (brow > bcol) return;                 // symmetry: upper triangle only
  const bool isdiag = (brow == bcol);
  const int tid = threadIdx.x;
  const int wave = tid >> 6, lane = tid & 63;
  const int wm = wave >> 1, wn = wave & 1;

  __shared__ short bufA[2][8 * 512];       // col panel, 8 chunks of 1KB
  __shared__ short bufB[2][8 * 512];       // row panel

  const int gi0 = brow * 8;                // row group base  -> B operand
  const int gj0 = bcol * 8;                // col group base  -> A operand

  // per-wave staging assignment: 4 chunks each (of 16)
  const short* gsrc[4];
  short* ldst0[4];
  short* ldst1[4];
#pragma unroll
  for (int q = 0; q < 4; ++q) {
    int c = wave * 4 + q;
    int g = (c < 8) ? (gj0 + c) : (gi0 + c - 8);
    gsrc[q] = Ft + (long)g * (KBN * 512) + lane * 8;
    if (c < 8) { ldst0[q] = &bufA[0][c * 512]; ldst1[q] = &bufA[1][c * 512]; }
    else       { ldst0[q] = &bufB[0][(c - 8) * 512]; ldst1[q] = &bufB[1][(c - 8) * 512]; }
  }

  f32x4 acc[4][4];                      // [fj][fi]
#pragma unroll
  for (int a = 0; a < 4; ++a)
#pragma unroll
    for (int b = 0; b < 4; ++b) acc[a][b] = (f32x4){0.f, 0.f, 0.f, 0.f};

  // prologue: stage kb=0 into buf 0
#pragma unroll
  for (int q = 0; q < 4; ++q) gload_lds16(gsrc[q] + 0 * 512, ldst0[q]);
  __syncthreads();

  int cur = 0;
  for (int kb = 0; kb < KBN; ++kb) {
    if (kb + 1 < KBN) {
#pragma unroll
      for (int q = 0; q < 4; ++q)
        gload_lds16(gsrc[q] + (kb + 1) * 512, cur ? ldst0[q] : ldst1[q]);
    }
    const short* pa = &bufA[cur][wn * 2048];
    const short* pb = &bufB[cur][wm * 2048];
    bf16x8 a[4], b[4];
#pragma unroll
    for (int f = 0; f < 4; ++f) {
      a[f] = *(const bf16x8*)(pa + f * 512 + lane * 16 - lane * 8);  // lane*8 shorts
      b[f] = *(const bf16x8*)(pb + f * 512 + lane * 8);
    }
    // (note: a[] address simplifies to + lane*8; written to match b[])
#pragma unroll
    for (int fj = 0; fj < 4; ++fj)
#pragma unroll
      for (int fi = 0; fi < 4; ++fi)
        acc[fj][fi] = __builtin_amdgcn_mfma_f32_16x16x32_bf16(a[fj], b[fi], acc[fj][fi], 0, 0, 0);
    __syncthreads();
    cur ^= 1;
  }

  // epilogue
  // D[fj][fi][reg] = sims[row = brow*128 + wm*64 + fi*16 + (lane&15)]
  //                      [col = bcol*128 + wn*64 + fj*16 + (lane>>4)*4 + reg]
  const int rowbase = brow * 128 + wm * 64;
  const int colbase = bcol * 128 + wn * 64;
  const int ln = lane & 15, lh = lane >> 4;

  float rs[4] = {0.f, 0.f, 0.f, 0.f};
  float ss[4] = {0.f, 0.f, 0.f, 0.f};
  float cs[4] = {0.f, 0.f, 0.f, 0.f};
  float mx[4] = {-1e30f, -1e30f, -1e30f, -1e30f};
  ulonglong2 rb[4];
  int rowv[4];
#pragma unroll
  for (int fi = 0; fi < 4; ++fi) {
    rowv[fi] = rowbase + fi * 16 + ln;
    rb[fi] = bits[rowv[fi]];
  }
#pragma unroll
  for (int fj = 0; fj < 4; ++fj) {
    float cr[4] = {0.f, 0.f, 0.f, 0.f};
    float cv[4] = {0.f, 0.f, 0.f, 0.f};
    float cn[4] = {0.f, 0.f, 0.f, 0.f};
#pragma unroll
    for (int reg = 0; reg < 4; ++reg) {
      const int col = colbase + fj * 16 + lh * 4 + reg;
      const ulonglong2 cb = bits[col];
#pragma unroll
      for (int fi = 0; fi < 4; ++fi) {
        float v = acc[fj][fi][reg] * 0.5f;   // sims = dot / TAU
        float e = __expf(v);
        bool dg = (col == rowv[fi]);
        bool ovl = ((rb[fi].x & cb.x) | (rb[fi].y & cb.y)) != 0ULL;
        mx[fi] = fmaxf(mx[fi], v);
        if (!dg) {
          rs[fi] += e;
          if (ovl) { ss[fi] += v; cs[fi] += 1.0f; }
          if (!isdiag) {             // column-role stats (symmetric partner)
            cr[reg] += e;
            if (ovl) { cv[reg] += v; cn[reg] += 1.0f; }
          }
        }
      }
    }
    if (!isdiag) {
      // reduce col partials across ln (16-lane groups share (lh,reg) -> same col)
#pragma unroll
      for (int reg = 0; reg < 4; ++reg) {
        float r = cr[reg], s = cv[reg], c = cn[reg];
#pragma unroll
        for (int d = 1; d < 16; d <<= 1) {
          r += __shfl_xor(r, d, 16);
          s += __shfl_xor(s, d, 16);
          c += __shfl_xor(c, d, 16);
        }
        if (ln == 0) {
          int col = colbase + fj * 16 + lh * 4 + reg;
          atomicAdd(R + col, r);
          atomicAdd(S + col, s);
          atomicAdd(Cc + col, c);
          // max skipped: row 'col' gets its true max (sims_cc = 0.5, the
          // row maximum by Cauchy-Schwarz) from its own diagonal block
        }
      }
    }
  }
#pragma unroll
  for (int fi = 0; fi < 4; ++fi) {
    float r = rs[fi], s = ss[fi], c = cs[fi], m = mx[fi];
    r += __shfl_xor(r, 16, 64); s += __shfl_xor(s, 16, 64);
    c += __shfl_xor(c, 16, 64); m = fmaxf(m, __shfl_xor(m, 16, 64));
    r += __shfl_xor(r, 32, 64); s += __shfl_xor(s, 32, 64);
    c += __shfl_xor(c, 32, 64); m = fmaxf(m, __shfl_xor(m, 32, 64));
    if (lane < 16) {
      int row = rowbase + fi * 16 + lane;
      atomicAdd(R + row, r);
      atomicAdd(S + row, s);
      atomicAdd(Cc + row, c);
      atomicMax(Mk + row, fkey(m));
    }
  }
}

__global__ void finalize_kernel(const float* __restrict__ R, const float* __restrict__ S,
                                const float* __restrict__ Cc, const unsigned* __restrict__ Mk,
                                const float* __restrict__ lm, float* __restrict__ out) {
  int tid = threadIdx.x;
  float s1 = 0.f, s2 = 0.f, slm = 0.f;
  for (int i = tid; i < NN; i += 256) {
    float r = R[i], s = S[i], c = Cc[i], l = lm[i];
    float logR = logf(r);
    float lp1 = (c > 0.f) ? (s - c * logR) / c : 0.f;
    unsigned k = Mk[i];
    float m = (k & 0x80000000u) ? __uint_as_float(k & 0x7fffffffu) : __uint_as_float(~k);
    float lp2 = (c == 0.f) ? (m - logR) : 0.f;   // -log(row_sum) = M - log(R0)
    s1 += lp1 * l; s2 += lp2; slm += l;
  }
#pragma unroll
  for (int d = 1; d < 64; d <<= 1) {
    s1 += __shfl_xor(s1, d, 64);
    s2 += __shfl_xor(s2, d, 64);
    slm += __shfl_xor(slm, d, 64);
  }
  __shared__ float w1[4], w2[4], w3[4];
  int w = tid >> 6;
  if ((tid & 63) == 0) { w1[w] = s1; w2[w] = s2; w3[w] = slm; }
  __syncthreads();
  if (tid == 0) {
    float a = 0.f, b = 0.f, c2 = 0.f;
    for (int i = 0; i < 4; ++i) { a += w1[i]; b += w2[i]; c2 += w3[i]; }
    const float inv = 1.0f / (float)NN;
    out[0] = -2.0f * (a * inv + b * c2 * inv * inv);
  }
}

extern "C" void kernel_launch(void* const* d_in, const int* in_sizes, int n_in,
                              void* d_out, int out_size, void* d_ws, size_t ws_size,
                              hipStream_t stream) {
  const float* F = (const float*)d_in[0];
  const int* labels = (const int*)d_in[1];
  float* out = (float*)d_out;
  char* ws = (char*)d_ws;

  short* Ft = (short*)(ws);
  float* R = (float*)(ws + OFF_R);
  float* S = (float*)(ws + OFF_S);
  float* Cc = (float*)(ws + OFF_C);
  unsigned* Mk = (unsigned*)(ws + OFF_M);
  ulonglong2* bits = (ulonglong2*)(ws + OFF_BITS);
  float* lm = (float*)(ws + OFF_LM);

  // zero R, S, C, M (contiguous 4 * NN * 4 bytes); key 0 < key(-inf) so max-init ok
  hipMemsetAsync(ws + OFF_R, 0, 4 * NN * 4, stream);
  prep_bits_kernel<<<NN / 4, 256, 0, stream>>>(labels, bits, lm);
  convert_kernel<<<(NN * DD / 8) / 256, 256, 0, stream>>>(F, Ft);
  dim3 grid(32, 32);
  main_kernel<<<grid, 256, 0, stream>>>(Ft, bits, R, S, Cc, Mk);
  finalize_kernel<<<1, 256, 0, stream>>>(R, S, Cc, Mk, lm, out);
}

// Round 3
// 75.427 us; speedup vs baseline: 1.1612x; 1.1567x over previous
//
#include <hip/hip_runtime.h>
#include <hip/hip_bf16.h>

#define NN 4096
#define DD 768
#define CCL 97
#define KBN 24               // DD/32 k-blocks
#define NTB 528              // 32*33/2 upper-triangle 128x128 tiles

typedef __attribute__((ext_vector_type(8))) short bf16x8;
typedef __attribute__((ext_vector_type(4))) float f32x4;

// workspace layout (bytes)
#define SZ_FT    (NN*DD*2)                // 6291456, bf16 fragment-tiled F
#define OFF_R    (SZ_FT)
#define OFF_S    (OFF_R + NN*4)
#define OFF_C    (OFF_S + NN*4)
#define OFF_M    (OFF_C + NN*4)
#define OFF_BITS (OFF_M + NN*4)           // 4096 * 16B
#define OFF_LM   (OFF_BITS + NN*16)

__device__ __forceinline__ unsigned fkey(float x) {
  unsigned u = __float_as_uint(x);
  return (u & 0x80000000u) ? ~u : (u | 0x80000000u);
}

// one wave per row: pack 97 labels into 2x u64 via ballot; label_mask
__global__ void prep_bits_kernel(const int* __restrict__ labels,
                                 ulonglong2* __restrict__ bits,
                                 float* __restrict__ lm) {
  int gw = (blockIdx.x * blockDim.x + threadIdx.x) >> 6;
  int lane = threadIdx.x & 63;
  if (gw >= NN) return;
  const int* lr = labels + (long)gw * CCL;
  int v0 = lr[lane];
  int c1 = 64 + lane;
  int v1 = (c1 < CCL) ? lr[c1] : 0;
  unsigned long long m0 = __ballot(v0 == 1);
  unsigned long long m1 = __ballot(v1 == 1);
  if (lane == 0) {
    bits[gw] = make_ulonglong2(m0, m1);
    lm[gw] = (lr[0] != 1) ? 1.0f : 0.0f;
  }
}

// f32 [N][D] -> bf16 fragment-tiled (tile t = g*KBN + kb; chunk c = ko*16 + ro)
__global__ void convert_kernel(const float* __restrict__ F, short* __restrict__ Ft) {
  int idx = blockIdx.x * 256 + threadIdx.x;
  int t = idx >> 6, c = idx & 63;
  int ko = c >> 4, ro = c & 15;
  int g = t / KBN, kb = t - g * KBN;
  int row = g * 16 + ro;
  int k0 = kb * 32 + ko * 8;
  const float* src = F + (long)row * DD + k0;
  union { __hip_bfloat16 h[8]; uint4 u; } p;
#pragma unroll
  for (int j = 0; j < 8; ++j) p.h[j] = __float2bfloat16(src[j]);
  *((uint4*)(Ft + (long)idx * 8)) = p.u;
}

__device__ __forceinline__ void gload_lds16(const short* gsrc, short* ldst) {
  __builtin_amdgcn_global_load_lds(
      (const __attribute__((address_space(1))) void*)gsrc,
      (__attribute__((address_space(3))) void*)ldst, 16, 0, 0);
}

#define WAITV(N) asm volatile("s_waitcnt vmcnt(" #N ")" ::: "memory")
#define WAITL0() asm volatile("s_waitcnt lgkmcnt(0)" ::: "memory")

// compact upper-triangle grid; 3-buffer LDS, counted-vmcnt pipeline
__global__ __launch_bounds__(256) void main_kernel(
    const short* __restrict__ Ft, const ulonglong2* __restrict__ bits,
    float* __restrict__ R, float* __restrict__ S, float* __restrict__ Cc,
    unsigned int* __restrict__ Mk) {
  __shared__ short lds[3][16 * 512];       // 3 x 16KB

  const int tid = threadIdx.x;
  const int wave = tid >> 6, lane = tid & 63;
  const int wm = wave >> 1, wn = wave & 1;

  // XCD swizzle (528 = 8*66, bijective) + triangular decode (i<=j)
  int b0 = blockIdx.x;
  int nb = (b0 & 7) * 66 + (b0 >> 3);
  int i = (int)((65.0f - sqrtf(4225.0f - 8.0f * (float)nb)) * 0.5f);
  while (32 * (i + 1) - ((i + 1) * i) / 2 <= nb) ++i;
  while (32 * i - (i * (i - 1)) / 2 > nb) --i;
  const int brow = i;
  const int bcol = nb - (32 * i - i * (i - 1) / 2) + i;
  const bool isdiag = (brow == bcol);

  // staging sources: 16 chunks of 1KB per k-step; wave stages chunks wave*4..+3
  const short* gs[4];
#pragma unroll
  for (int q = 0; q < 4; ++q) {
    int cc = wave * 4 + q;
    int g = (cc < 8) ? (bcol * 8 + cc) : (brow * 8 + (cc - 8));
    gs[q] = Ft + (long)g * (KBN * 512) + lane * 8;
  }

#define STAGE(kb, bi) do {                                            \
    short* lb = &lds[bi][0];                                          \
    _Pragma("unroll")                                                 \
    for (int q = 0; q < 4; ++q)                                       \
      gload_lds16(gs[q] + (kb) * 512, lb + (wave * 4 + q) * 512);     \
  } while (0)

  f32x4 acc[4][4];
#pragma unroll
  for (int a = 0; a < 4; ++a)
#pragma unroll
    for (int b = 0; b < 4; ++b) acc[a][b] = (f32x4){0.f, 0.f, 0.f, 0.f};

  STAGE(0, 0);
  STAGE(1, 1);

  int cur = 0;
  for (int kb = 0; kb < KBN; ++kb) {
    if (kb + 2 < KBN) {
      int bi = cur + 2; if (bi >= 3) bi -= 3;
      STAGE(kb + 2, bi);
    }
    if (kb < KBN - 2)      WAITV(8);   // stages kb+1, kb+2 stay in flight
    else if (kb == KBN - 2) WAITV(4);
    else                    WAITV(0);
    __builtin_amdgcn_s_barrier();

    const short* pa = &lds[cur][wn * 4 * 512] + lane * 8;
    const short* pb = &lds[cur][(8 + wm * 4) * 512] + lane * 8;
    bf16x8 af[4], bf[4];
#pragma unroll
    for (int f = 0; f < 4; ++f) {
      af[f] = *(const bf16x8*)(pa + f * 512);
      bf[f] = *(const bf16x8*)(pb + f * 512);
    }
    __builtin_amdgcn_s_setprio(1);
#pragma unroll
    for (int fj = 0; fj < 4; ++fj)
#pragma unroll
      for (int fi = 0; fi < 4; ++fi)
        acc[fj][fi] = __builtin_amdgcn_mfma_f32_16x16x32_bf16(af[fj], bf[fi], acc[fj][fi], 0, 0, 0);
    __builtin_amdgcn_s_setprio(0);
    WAITL0();                            // all reads of lds[cur] landed
    __builtin_amdgcn_s_barrier();        // before lds[cur] is re-staged
    cur = (cur == 2) ? 0 : cur + 1;
  }

  // epilogue
  // D[fj][fi][reg] = sims[row = brow*128 + wm*64 + fi*16 + (lane&15)]
  //                      [col = bcol*128 + wn*64 + fj*16 + (lane>>4)*4 + reg]
  const int rowbase = brow * 128 + wm * 64;
  const int colbase = bcol * 128 + wn * 64;
  const int ln = lane & 15, lh = lane >> 4;

  float rs[4] = {0.f, 0.f, 0.f, 0.f};
  float ss[4] = {0.f, 0.f, 0.f, 0.f};
  float cs[4] = {0.f, 0.f, 0.f, 0.f};
  float mx[4] = {-1e30f, -1e30f, -1e30f, -1e30f};
  ulonglong2 rb[4];
  int rowv[4];
#pragma unroll
  for (int fi = 0; fi < 4; ++fi) {
    rowv[fi] = rowbase + fi * 16 + ln;
    rb[fi] = bits[rowv[fi]];
  }
#pragma unroll
  for (int fj = 0; fj < 4; ++fj) {
    float cr[4] = {0.f, 0.f, 0.f, 0.f};
    float cv[4] = {0.f, 0.f, 0.f, 0.f};
    float cn[4] = {0.f, 0.f, 0.f, 0.f};
#pragma unroll
    for (int reg = 0; reg < 4; ++reg) {
      const int col = colbase + fj * 16 + lh * 4 + reg;
      const ulonglong2 cb = bits[col];
#pragma unroll
      for (int fi = 0; fi < 4; ++fi) {
        float v = acc[fj][fi][reg] * 0.5f;   // sims = dot / TAU
        float e = __expf(v);
        bool dg = (col == rowv[fi]);
        bool ovl = ((rb[fi].x & cb.x) | (rb[fi].y & cb.y)) != 0ULL;
        mx[fi] = fmaxf(mx[fi], v);
        if (!dg) {
          rs[fi] += e;
          if (ovl) { ss[fi] += v; cs[fi] += 1.0f; }
          if (!isdiag) {
            cr[reg] += e;
            if (ovl) { cv[reg] += v; cn[reg] += 1.0f; }
          }
        }
      }
    }
    if (!isdiag) {
#pragma unroll
      for (int reg = 0; reg < 4; ++reg) {
        float r = cr[reg], s = cv[reg], c = cn[reg];
#pragma unroll
        for (int d = 1; d < 16; d <<= 1) {
          r += __shfl_xor(r, d, 16);
          s += __shfl_xor(s, d, 16);
          c += __shfl_xor(c, d, 16);
        }
        if (ln == 0) {
          int col = colbase + fj * 16 + lh * 4 + reg;
          atomicAdd(R + col, r);
          atomicAdd(S + col, s);
          atomicAdd(Cc + col, c);
          // col-row max comes from that row's own diagonal block (sims_cc = max)
        }
      }
    }
  }
#pragma unroll
  for (int fi = 0; fi < 4; ++fi) {
    float r = rs[fi], s = ss[fi], c = cs[fi], m = mx[fi];
    r += __shfl_xor(r, 16, 64); s += __shfl_xor(s, 16, 64);
    c += __shfl_xor(c, 16, 64); m = fmaxf(m, __shfl_xor(m, 16, 64));
    r += __shfl_xor(r, 32, 64); s += __shfl_xor(s, 32, 64);
    c += __shfl_xor(c, 32, 64); m = fmaxf(m, __shfl_xor(m, 32, 64));
    if (lane < 16) {
      int row = rowbase + fi * 16 + lane;
      atomicAdd(R + row, r);
      atomicAdd(S + row, s);
      atomicAdd(Cc + row, c);
      atomicMax(Mk + row, fkey(m));
    }
  }
#undef STAGE
}

__global__ void finalize_kernel(const float* __restrict__ R, const float* __restrict__ S,
                                const float* __restrict__ Cc, const unsigned* __restrict__ Mk,
                                const float* __restrict__ lm, float* __restrict__ out) {
  int tid = threadIdx.x;
  float s1 = 0.f, s2 = 0.f, slm = 0.f;
  for (int i = tid; i < NN; i += 256) {
    float r = R[i], s = S[i], c = Cc[i], l = lm[i];
    float logR = logf(r);
    float lp1 = (c > 0.f) ? (s - c * logR) / c : 0.f;
    unsigned k = Mk[i];
    float m = (k & 0x80000000u) ? __uint_as_float(k & 0x7fffffffu) : __uint_as_float(~k);
    float lp2 = (c == 0.f) ? (m - logR) : 0.f;   // -log(row_sum) = M - log(R0)
    s1 += lp1 * l; s2 += lp2; slm += l;
  }
#pragma unroll
  for (int d = 1; d < 64; d <<= 1) {
    s1 += __shfl_xor(s1, d, 64);
    s2 += __shfl_xor(s2, d, 64);
    slm += __shfl_xor(slm, d, 64);
  }
  __shared__ float w1[4], w2[4], w3[4];
  int w = tid >> 6;
  if ((tid & 63) == 0) { w1[w] = s1; w2[w] = s2; w3[w] = slm; }
  __syncthreads();
  if (tid == 0) {
    float a = 0.f, b = 0.f, c2 = 0.f;
    for (int i = 0; i < 4; ++i) { a += w1[i]; b += w2[i]; c2 += w3[i]; }
    const float inv = 1.0f / (float)NN;
    out[0] = -2.0f * (a * inv + b * c2 * inv * inv);
  }
}

extern "C" void kernel_launch(void* const* d_in, const int* in_sizes, int n_in,
                              void* d_out, int out_size, void* d_ws, size_t ws_size,
                              hipStream_t stream) {
  const float* F = (const float*)d_in[0];
  const int* labels = (const int*)d_in[1];
  float* out = (float*)d_out;
  char* ws = (char*)d_ws;

  short* Ft = (short*)(ws);
  float* R = (float*)(ws + OFF_R);
  float* S = (float*)(ws + OFF_S);
  float* Cc = (float*)(ws + OFF_C);
  unsigned* Mk = (unsigned*)(ws + OFF_M);
  ulonglong2* bits = (ulonglong2*)(ws + OFF_BITS);
  float* lm = (float*)(ws + OFF_LM);

  hipMemsetAsync(ws + OFF_R, 0, 4 * NN * 4, stream);
  prep_bits_kernel<<<NN / 4, 256, 0, stream>>>(labels, bits, lm);
  convert_kernel<<<(NN * DD / 8) / 256, 256, 0, stream>>>(F, Ft);
  main_kernel<<<NTB, 256, 0, stream>>>(Ft, bits, R, S, Cc, Mk);
  finalize_kernel<<<1, 256, 0, stream>>>(R, S, Cc, Mk, lm, out);
}

// Round 4
// 64.335 us; speedup vs baseline: 1.3613x; 1.1724x over previous
//
#include <hip/hip_runtime.h>
#include <hip/hip_bf16.h>

#define NN 4096
#define DD 768
#define CCL 97
#define KBN 24               // DD/32 k-blocks
#define NTB 528              // 32*33/2 upper-triangle 128x128 tiles

typedef __attribute__((ext_vector_type(8))) short bf16x8;
typedef __attribute__((ext_vector_type(4))) float f32x4;

// workspace layout (bytes)
#define SZ_FT    (NN*DD*2)                // bf16 fragment-tiled F
#define OFF_R    (SZ_FT)
#define OFF_S    (OFF_R + NN*4)
#define OFF_C    (OFF_S + NN*4)
#define OFF_M    (OFF_C + NN*4)
#define OFF_BITS (OFF_M + NN*4)           // 4096 * 16B
#define OFF_LM   (OFF_BITS + NN*16)

__device__ __forceinline__ unsigned fkey(float x) {
  unsigned u = __float_as_uint(x);
  return (u & 0x80000000u) ? ~u : (u | 0x80000000u);
}

// one wave per row: pack 97 labels into 2x u64 via ballot; label_mask; zero accums
__global__ void prep_bits_kernel(const int* __restrict__ labels,
                                 ulonglong2* __restrict__ bits,
                                 float* __restrict__ lm,
                                 float* __restrict__ R, float* __restrict__ S,
                                 float* __restrict__ Cc, unsigned* __restrict__ Mk) {
  int gw = (blockIdx.x * blockDim.x + threadIdx.x) >> 6;
  int lane = threadIdx.x & 63;
  if (gw >= NN) return;
  const int* lr = labels + (long)gw * CCL;
  int v0 = lr[lane];
  int c1 = 64 + lane;
  int v1 = (c1 < CCL) ? lr[c1] : 0;
  unsigned long long m0 = __ballot(v0 == 1);
  unsigned long long m1 = __ballot(v1 == 1);
  if (lane == 0) {
    bits[gw] = make_ulonglong2(m0, m1);
    lm[gw] = (lr[0] != 1) ? 1.0f : 0.0f;
    R[gw] = 0.f; S[gw] = 0.f; Cc[gw] = 0.f; Mk[gw] = 0u;  // key 0 < fkey(any)
  }
}

// f32 [N][D] -> bf16 fragment-tiled, read-coalesced (thread = 8 consecutive k)
// tile t = (r/16)*KBN + k0/32; chunk c = ((k0/8)%4)*16 + r%16; out = t*512 + c*8
__global__ void convert_kernel(const float* __restrict__ F, short* __restrict__ Ft) {
  int idx = blockIdx.x * 256 + threadIdx.x;      // 0 .. NN*96-1
  int r = idx / 96, kc = idx - r * 96;
  const float* src = F + (long)r * DD + kc * 8;
  union { __hip_bfloat16 h[8]; uint4 u; } p;
#pragma unroll
  for (int j = 0; j < 8; ++j) p.h[j] = __float2bfloat16(src[j]);
  int t = (r >> 4) * KBN + (kc >> 2);
  int c = (kc & 3) * 16 + (r & 15);
  *((uint4*)(Ft + (long)t * 512 + c * 8)) = p.u;
}

__device__ __forceinline__ void gload_lds16(const short* gsrc, short* ldst) {
  __builtin_amdgcn_global_load_lds(
      (const __attribute__((address_space(1))) void*)gsrc,
      (__attribute__((address_space(3))) void*)ldst, 16, 0, 0);
}

#define WAITV(N) asm volatile("s_waitcnt vmcnt(" #N ")" ::: "memory")

// compact upper-triangle grid; 3-buffer LDS; ONE barrier per K-step, counted vmcnt
__global__ __launch_bounds__(256) void main_kernel(
    const short* __restrict__ Ft, const ulonglong2* __restrict__ bits,
    float* __restrict__ R, float* __restrict__ S, float* __restrict__ Cc,
    unsigned int* __restrict__ Mk) {
  __shared__ short lds[3][16 * 512];       // 3 x 16KB -> 3 blocks/CU

  const int tid = threadIdx.x;
  const int wave = tid >> 6, lane = tid & 63;
  const int wm = wave >> 1, wn = wave & 1;

  // XCD swizzle (528 = 8*66, bijective) + triangular decode (i<=j)
  int b0 = blockIdx.x;
  int nb = (b0 & 7) * 66 + (b0 >> 3);
  int i = (int)((65.0f - sqrtf(4225.0f - 8.0f * (float)nb)) * 0.5f);
  while (32 * (i + 1) - ((i + 1) * i) / 2 <= nb) ++i;
  while (32 * i - (i * (i - 1)) / 2 > nb) --i;
  const int brow = i;
  const int bcol = nb - (32 * i - i * (i - 1) / 2) + i;
  const bool isdiag = (brow == bcol);

  // staging sources: 16 chunks of 1KB per k-step; wave stages chunks wave*4..+3
  const short* gs[4];
#pragma unroll
  for (int q = 0; q < 4; ++q) {
    int cc = wave * 4 + q;
    int g = (cc < 8) ? (bcol * 8 + cc) : (brow * 8 + (cc - 8));
    gs[q] = Ft + (long)g * (KBN * 512) + lane * 8;
  }

#define STAGE(kb, bi) do {                                            \
    short* lb = &lds[bi][0];                                          \
    _Pragma("unroll")                                                 \
    for (int q = 0; q < 4; ++q)                                       \
      gload_lds16(gs[q] + (kb) * 512, lb + (wave * 4 + q) * 512);     \
  } while (0)

  f32x4 acc[4][4];
#pragma unroll
  for (int a = 0; a < 4; ++a)
#pragma unroll
    for (int b = 0; b < 4; ++b) acc[a][b] = (f32x4){0.f, 0.f, 0.f, 0.f};

  STAGE(0, 0);
  STAGE(1, 1);

  int cur = 0;
  for (int kb = 0; kb < KBN; ++kb) {
    // steady state: outstanding = kb(4) + kb+1(4); drain kb only, keep kb+1 in flight
    if (kb < KBN - 1) WAITV(4);
    else              WAITV(0);
    __builtin_amdgcn_s_barrier();          // all waves done reading buf (kb-1)%3
    asm volatile("" ::: "memory");         // no mem op crosses above the barrier
    if (kb + 2 < KBN) {
      int nxt = cur + 2; if (nxt >= 3) nxt -= 3;
      STAGE(kb + 2, nxt);                  // overwrites buf computed at kb-1: safe
    }
    const short* pa = &lds[cur][wn * 4 * 512] + lane * 8;
    const short* pb = &lds[cur][(8 + wm * 4) * 512] + lane * 8;
    bf16x8 af[4], bf[4];
#pragma unroll
    for (int f = 0; f < 4; ++f) {
      af[f] = *(const bf16x8*)(pa + f * 512);
      bf[f] = *(const bf16x8*)(pb + f * 512);
    }
    __builtin_amdgcn_s_setprio(1);
#pragma unroll
    for (int fj = 0; fj < 4; ++fj)
#pragma unroll
      for (int fi = 0; fi < 4; ++fi)
        acc[fj][fi] = __builtin_amdgcn_mfma_f32_16x16x32_bf16(af[fj], bf[fi], acc[fj][fi], 0, 0, 0);
    __builtin_amdgcn_s_setprio(0);
    // no second barrier: compiler's lgkmcnt before MFMA guarantees our reads of
    // lds[cur] completed before we reach the NEXT iteration's barrier
    cur = (cur == 2) ? 0 : cur + 1;
  }

  // epilogue
  // D[fj][fi][reg] = sims[row = brow*128 + wm*64 + fi*16 + (lane&15)]
  //                      [col = bcol*128 + wn*64 + fj*16 + (lane>>4)*4 + reg]
  const int rowbase = brow * 128 + wm * 64;
  const int colbase = bcol * 128 + wn * 64;
  const int ln = lane & 15, lh = lane >> 4;

  float rs[4] = {0.f, 0.f, 0.f, 0.f};
  float ss[4] = {0.f, 0.f, 0.f, 0.f};
  float cs[4] = {0.f, 0.f, 0.f, 0.f};
  float mx[4] = {-1e30f, -1e30f, -1e30f, -1e30f};
  ulonglong2 rb[4];
  int rowv[4];
#pragma unroll
  for (int fi = 0; fi < 4; ++fi) {
    rowv[fi] = rowbase + fi * 16 + ln;
    rb[fi] = bits[rowv[fi]];
  }
#pragma unroll
  for (int fj = 0; fj < 4; ++fj) {
    float cr[4] = {0.f, 0.f, 0.f, 0.f};
    float cv[4] = {0.f, 0.f, 0.f, 0.f};
    float cn[4] = {0.f, 0.f, 0.f, 0.f};
#pragma unroll
    for (int reg = 0; reg < 4; ++reg) {
      const int col = colbase + fj * 16 + lh * 4 + reg;
      const ulonglong2 cb = bits[col];
#pragma unroll
      for (int fi = 0; fi < 4; ++fi) {
        float v = acc[fj][fi][reg] * 0.5f;   // sims = dot / TAU
        float e = __expf(v);
        bool dg = (col == rowv[fi]);
        bool ovl = ((rb[fi].x & cb.x) | (rb[fi].y & cb.y)) != 0ULL;
        mx[fi] = fmaxf(mx[fi], v);
        if (!dg) {
          rs[fi] += e;
          if (ovl) { ss[fi] += v; cs[fi] += 1.0f; }
          if (!isdiag) {
            cr[reg] += e;
            if (ovl) { cv[reg] += v; cn[reg] += 1.0f; }
          }
        }
      }
    }
    if (!isdiag) {
#pragma unroll
      for (int reg = 0; reg < 4; ++reg) {
        float r = cr[reg], s = cv[reg], c = cn[reg];
#pragma unroll
        for (int d = 1; d < 16; d <<= 1) {
          r += __shfl_xor(r, d, 16);
          s += __shfl_xor(s, d, 16);
          c += __shfl_xor(c, d, 16);
        }
        if (ln == 0) {
          int col = colbase + fj * 16 + lh * 4 + reg;
          atomicAdd(R + col, r);
          atomicAdd(S + col, s);
          atomicAdd(Cc + col, c);
          // col-row max comes from that row's own diagonal block (sims_cc = max)
        }
      }
    }
  }
#pragma unroll
  for (int fi = 0; fi < 4; ++fi) {
    float r = rs[fi], s = ss[fi], c = cs[fi], m = mx[fi];
    r += __shfl_xor(r, 16, 64); s += __shfl_xor(s, 16, 64);
    c += __shfl_xor(c, 16, 64); m = fmaxf(m, __shfl_xor(m, 16, 64));
    r += __shfl_xor(r, 32, 64); s += __shfl_xor(s, 32, 64);
    c += __shfl_xor(c, 32, 64); m = fmaxf(m, __shfl_xor(m, 32, 64));
    if (lane < 16) {
      int row = rowbase + fi * 16 + lane;
      atomicAdd(R + row, r);
      atomicAdd(S + row, s);
      atomicAdd(Cc + row, c);
      atomicMax(Mk + row, fkey(m));
    }
  }
#undef STAGE
}

__global__ __launch_bounds__(1024) void finalize_kernel(
    const float* __restrict__ R, const float* __restrict__ S,
    const float* __restrict__ Cc, const unsigned* __restrict__ Mk,
    const float* __restrict__ lm, float* __restrict__ out) {
  int tid = threadIdx.x;
  float s1 = 0.f, s2 = 0.f, slm = 0.f;
  for (int i = tid; i < NN; i += 1024) {
    float r = R[i], s = S[i], c = Cc[i], l = lm[i];
    float logR = logf(r);
    float lp1 = (c > 0.f) ? (s - c * logR) / c : 0.f;
    unsigned k = Mk[i];
    float m = (k & 0x80000000u) ? __uint_as_float(k & 0x7fffffffu) : __uint_as_float(~k);
    float lp2 = (c == 0.f) ? (m - logR) : 0.f;   // -log(row_sum) = M - log(R0)
    s1 += lp1 * l; s2 += lp2; slm += l;
  }
#pragma unroll
  for (int d = 1; d < 64; d <<= 1) {
    s1 += __shfl_xor(s1, d, 64);
    s2 += __shfl_xor(s2, d, 64);
    slm += __shfl_xor(slm, d, 64);
  }
  __shared__ float w1[16], w2[16], w3[16];
  int w = tid >> 6;
  if ((tid & 63) == 0) { w1[w] = s1; w2[w] = s2; w3[w] = slm; }
  __syncthreads();
  if (tid == 0) {
    float a = 0.f, b = 0.f, c2 = 0.f;
    for (int i2 = 0; i2 < 16; ++i2) { a += w1[i2]; b += w2[i2]; c2 += w3[i2]; }
    const float inv = 1.0f / (float)NN;
    out[0] = -2.0f * (a * inv + b * c2 * inv * inv);
  }
}

extern "C" void kernel_launch(void* const* d_in, const int* in_sizes, int n_in,
                              void* d_out, int out_size, void* d_ws, size_t ws_size,
                              hipStream_t stream) {
  const float* F = (const float*)d_in[0];
  const int* labels = (const int*)d_in[1];
  float* out = (float*)d_out;
  char* ws = (char*)d_ws;

  short* Ft = (short*)(ws);
  float* R = (float*)(ws + OFF_R);
  float* S = (float*)(ws + OFF_S);
  float* Cc = (float*)(ws + OFF_C);
  unsigned* Mk = (unsigned*)(ws + OFF_M);
  ulonglong2* bits = (ulonglong2*)(ws + OFF_BITS);
  float* lm = (float*)(ws + OFF_LM);

  prep_bits_kernel<<<NN / 4, 256, 0, stream>>>(labels, bits, lm, R, S, Cc, Mk);
  convert_kernel<<<(NN * 96) / 256, 256, 0, stream>>>(F, Ft);
  main_kernel<<<NTB, 256, 0, stream>>>(Ft, bits, R, S, Cc, Mk);
  finalize_kernel<<<1, 1024, 0, stream>>>(R, S, Cc, Mk, lm, out);
}